// Round 3
// baseline (619.045 us; speedup 1.0000x reference)
//
#include <hip/hip_runtime.h>

#define NIN 64
#define NOUT 32
#define TBITS 21                 // 128^3 stride-2 lattice
#define TSIZE (1 << TBITS)

// ws layout:
//   [0, 8MB)              : table (2^21 int)
//   [8MB, 8MB+4*Ng)       : sorted guide ids
//   then 16 ints          : count[8], cursor[8]

// ---- fill direct table with -1; zero class counters ----
__global__ void init_table4(int4* __restrict__ table, int n4, int* __restrict__ count) {
    int i = blockIdx.x * blockDim.x + threadIdx.x;
    if (i < n4) table[i] = make_int4(-1, -1, -1, -1);
    if (blockIdx.x == 0 && threadIdx.x < 8) count[threadIdx.x] = 0;
}

// ---- scatter input point indices into the dense stride-2 lattice table ----
__global__ void build_table(const int* __restrict__ coords, int np,
                            int* __restrict__ table) {
    int i = blockIdx.x * blockDim.x + threadIdx.x;
    if (i >= np) return;
    int x = coords[i * 4 + 1];
    int y = coords[i * 4 + 2];
    int z = coords[i * 4 + 3];
    int lin = (x >> 1) | ((y >> 1) << 7) | ((z >> 1) << 14);
    table[lin] = i;
}

// ---- count guides per parity class (8 classes) ----
__global__ void count_classes(const int* __restrict__ guide, int ng,
                              int* __restrict__ count) {
    __shared__ int lc[8];
    if (threadIdx.x < 8) lc[threadIdx.x] = 0;
    __syncthreads();
    int g = blockIdx.x * blockDim.x + threadIdx.x;
    if (g < ng) {
        int4 q = ((const int4*)guide)[g];
        int c = (q.y & 1) | ((q.z & 1) << 1) | ((q.w & 1) << 2);
        atomicAdd(&lc[c], 1);
    }
    __syncthreads();
    if (threadIdx.x < 8 && lc[threadIdx.x]) atomicAdd(&count[threadIdx.x], lc[threadIdx.x]);
}

// ---- exclusive scan of 8 counts -> cursor ----
__global__ void scan8(const int* __restrict__ count, int* __restrict__ cursor) {
    if (threadIdx.x == 0 && blockIdx.x == 0) {
        int s = 0;
        for (int c = 0; c < 8; ++c) { cursor[c] = s; s += count[c]; }
    }
}

// ---- scatter guide ids into class-sorted order ----
__global__ void scatter_guides(const int* __restrict__ guide, int ng,
                               int* __restrict__ cursor, int* __restrict__ sorted) {
    __shared__ int lc[8];
    __shared__ int lbase[8];
    int t = threadIdx.x;
    if (t < 8) lc[t] = 0;
    __syncthreads();
    int g = blockIdx.x * blockDim.x + t;
    int c = 0, lrank = 0;
    bool ok = g < ng;
    if (ok) {
        int4 q = ((const int4*)guide)[g];
        c = (q.y & 1) | ((q.z & 1) << 1) | ((q.w & 1) << 2);
        lrank = atomicAdd(&lc[c], 1);
    }
    __syncthreads();
    if (t < 8) lbase[t] = lc[t] ? atomicAdd(&cursor[t], lc[t]) : 0;
    __syncthreads();
    if (ok) sorted[lbase[c] + lrank] = g;
}

// ---- main: 8 lanes per guide, guides class-sorted so a wave's 8 guides share
// parity class. Hit loop iterates the wave-union of hit slots; at a given slot
// all same-class groups use the SAME W[oi] -> weight loads coalesce to one
// 128B line per instruction. Each lane accumulates 4 output channels. ----
__launch_bounds__(256, 4)
__global__ void gen_conv(const float* __restrict__ feats,     // [Np,64]
                         const float* __restrict__ weights,   // [27,64,32]
                         const float* __restrict__ bias,      // [32]
                         const int*  __restrict__ guide,      // [Ng,4]
                         const int*  __restrict__ table,      // [2^21]
                         const int*  __restrict__ sorted,     // [Ng]
                         float* __restrict__ out, int ng) {
    int tid  = blockIdx.x * blockDim.x + threadIdx.x;
    int gi   = tid >> 3;              // position in sorted list
    int sub  = threadIdx.x & 7;       // combo id / channel-quad id
    int lane = threadIdx.x & 63;
    int grp  = lane >> 3;             // group within wave (0..7)
    bool gok = gi < ng;
    int g = gok ? sorted[gi] : 0;

    int4 q = ((const int4*)guide)[g];
    int qx = q.y, qy = q.z, qz = q.w;

    // parity: odd component -> off in {-1,+1} (chosen by bit); even -> off=0
    int ex = qx & 1, ey = qy & 1, ez = qz & 1;
    int exmask = ex | (ey << 1) | (ez << 2);
    int b0 = sub & 1, b1 = (sub >> 1) & 1, b2 = (sub >> 2) & 1;
    int offx = ex ? (b0 ? 1 : -1) : 0;
    int offy = ey ? (b1 ? 1 : -1) : 0;
    int offz = ez ? (b2 ? 1 : -1) : 0;
    int px = qx - offx, py = qy - offy, pz = qz - offz;
    // dedupe (bit set on even component -> duplicate combo) + bounds
    bool valid = gok & ((sub & ~exmask & 7) == 0) &
                 ((unsigned)px < 256u) & ((unsigned)py < 256u) & ((unsigned)pz < 256u);
    int lin = (px >> 1) | ((py >> 1) << 7) | ((pz >> 1) << 14);
    int idx = table[valid ? lin : 0];
    idx = valid ? idx : -1;
    int oi = (offx + 1) * 9 + (offy + 1) * 3 + (offz + 1);

    unsigned long long m = __ballot(idx >= 0);
    // union over the 8 groups' slot masks (wave-uniform)
    unsigned long long z = m | (m >> 32);
    unsigned um = (unsigned)z;
    um |= um >> 16; um |= um >> 8; um &= 0xffu;
    bool exists = ((m >> (grp * 8)) & 0xffull) != 0;

    float4 acc = make_float4(0.f, 0.f, 0.f, 0.f);

    while (um) {
        int s = __builtin_ctz(um);
        um &= um - 1;
        int src  = (grp << 3) | s;
        int hidx = __shfl(idx, src, 64);
        int hoi  = __shfl(oi,  src, 64);
        if (hidx >= 0) {
            const float4* f4 = (const float4*)(feats + (size_t)hidx * NIN);
            const float4* w4 = (const float4*)(weights + (size_t)hoi * (NIN * NOUT)) + sub;
            #pragma unroll
            for (int k4 = 0; k4 < NIN / 4; ++k4) {
                float4 f  = f4[k4];
                float4 wa = w4[(k4 * 4 + 0) * (NOUT / 4)];
                float4 wb = w4[(k4 * 4 + 1) * (NOUT / 4)];
                float4 wc = w4[(k4 * 4 + 2) * (NOUT / 4)];
                float4 wd = w4[(k4 * 4 + 3) * (NOUT / 4)];
                acc.x = fmaf(f.x, wa.x, acc.x); acc.y = fmaf(f.x, wa.y, acc.y);
                acc.z = fmaf(f.x, wa.z, acc.z); acc.w = fmaf(f.x, wa.w, acc.w);
                acc.x = fmaf(f.y, wb.x, acc.x); acc.y = fmaf(f.y, wb.y, acc.y);
                acc.z = fmaf(f.y, wb.z, acc.z); acc.w = fmaf(f.y, wb.w, acc.w);
                acc.x = fmaf(f.z, wc.x, acc.x); acc.y = fmaf(f.z, wc.y, acc.y);
                acc.z = fmaf(f.z, wc.z, acc.z); acc.w = fmaf(f.z, wc.w, acc.w);
                acc.x = fmaf(f.w, wd.x, acc.x); acc.y = fmaf(f.w, wd.y, acc.y);
                acc.z = fmaf(f.w, wd.z, acc.z); acc.w = fmaf(f.w, wd.w, acc.w);
            }
        }
    }

    if (gok) {
        float4 r = make_float4(0.f, 0.f, 0.f, 0.f);
        if (exists) {
            float4 bv = ((const float4*)bias)[sub];
            r.x = acc.x + bv.x; r.y = acc.y + bv.y;
            r.z = acc.z + bv.z; r.w = acc.w + bv.w;
        }
        ((float4*)out)[(size_t)g * (NOUT / 4) + sub] = r;
    }
}

extern "C" void kernel_launch(void* const* d_in, const int* in_sizes, int n_in,
                              void* d_out, int out_size, void* d_ws, size_t ws_size,
                              hipStream_t stream) {
    const float* feats   = (const float*)d_in[0];
    const float* weights = (const float*)d_in[1];
    const float* bias    = (const float*)d_in[2];
    const int*   coords  = (const int*)d_in[3];
    const int*   guide   = (const int*)d_in[4];
    float* out = (float*)d_out;

    int np = in_sizes[3] / 4;
    int ng = in_sizes[4] / 4;

    char* ws = (char*)d_ws;
    int* table  = (int*)ws;                               // 8 MB
    int* sorted = (int*)(ws + (size_t)TSIZE * 4);         // 4*ng
    int* count  = (int*)(ws + (size_t)TSIZE * 4 + (size_t)ng * 4);  // 8 ints
    int* cursor = count + 8;                              // 8 ints

    hipLaunchKernelGGL(init_table4, dim3(TSIZE / 4 / 256), dim3(256), 0, stream,
                       (int4*)table, TSIZE / 4, count);
    hipLaunchKernelGGL(build_table, dim3((np + 255) / 256), dim3(256), 0, stream,
                       coords, np, table);
    hipLaunchKernelGGL(count_classes, dim3((ng + 255) / 256), dim3(256), 0, stream,
                       guide, ng, count);
    hipLaunchKernelGGL(scan8, dim3(1), dim3(64), 0, stream, count, cursor);
    hipLaunchKernelGGL(scatter_guides, dim3((ng + 255) / 256), dim3(256), 0, stream,
                       guide, ng, cursor, sorted);

    long long threads = (long long)ng * 8;
    int blocks = (int)((threads + 255) / 256);
    hipLaunchKernelGGL(gen_conv, dim3(blocks), dim3(256), 0, stream,
                       feats, weights, bias, guide, table, sorted, out, ng);
}

// Round 4
// 313.911 us; speedup vs baseline: 1.9720x; 1.9720x over previous
//
#include <hip/hip_runtime.h>

#define NIN 64
#define NOUT 32
#define TBITS 21                 // 128^3 stride-2 lattice
#define TSIZE (1 << TBITS)

// ---- fill direct table with -1 (ws is poisoned 0xAA every call) ----
__global__ void init_table4(int4* __restrict__ table, int n4) {
    int i = blockIdx.x * blockDim.x + threadIdx.x;
    if (i < n4) table[i] = make_int4(-1, -1, -1, -1);
}

// ---- scatter input point indices into the dense stride-2 lattice table ----
__global__ void build_table(const int* __restrict__ coords, int np,
                            int* __restrict__ table) {
    int i = blockIdx.x * blockDim.x + threadIdx.x;
    if (i >= np) return;
    int x = coords[i * 4 + 1];
    int y = coords[i * 4 + 2];
    int z = coords[i * 4 + 3];
    int lin = (x >> 1) | ((y >> 1) << 7) | ((z >> 1) << 14);
    table[lin] = i;
}

// ---- main: 32 lanes per guide. lane = (ksec 0..3, sub 0..7).
// sub enumerates the <=8 parity-admissible offsets (probe replicated over
// ksec -> broadcast load). Per hit, each lane covers k-range of 16 for its
// 4 output channels -> 4x shorter dependency chain + 4x loads in flight vs
// 8-lane groups. Final __shfl_xor(8/16) reduces the 4 k-sections. ----
__launch_bounds__(256)
__global__ void gen_conv(const float* __restrict__ feats,     // [Np,64]
                         const float* __restrict__ weights,   // [27,64,32]
                         const float* __restrict__ bias,      // [32]
                         const int*  __restrict__ guide,      // [Ng,4]
                         const int*  __restrict__ table,      // [2^21]
                         float* __restrict__ out, int ng) {
    int tid  = blockIdx.x * blockDim.x + threadIdx.x;
    int g    = tid >> 5;              // guide index (32 lanes per guide)
    int l5   = threadIdx.x & 31;
    int sub  = l5 & 7;                // probe slot / channel-quad id
    int ksec = l5 >> 3;               // k section (0..3)
    int lane = threadIdx.x & 63;
    int half = lane >> 5;             // which guide-group within the wave
    bool gok = g < ng;
    int gg = gok ? g : 0;

    int4 q = ((const int4*)guide)[gg];
    int qx = q.y, qy = q.z, qz = q.w;

    // parity: odd component -> off in {-1,+1} (chosen by bit); even -> off=0
    int ex = qx & 1, ey = qy & 1, ez = qz & 1;
    int exmask = ex | (ey << 1) | (ez << 2);
    int b0 = sub & 1, b1 = (sub >> 1) & 1, b2 = (sub >> 2) & 1;
    int offx = ex ? (b0 ? 1 : -1) : 0;
    int offy = ey ? (b1 ? 1 : -1) : 0;
    int offz = ez ? (b2 ? 1 : -1) : 0;
    int px = qx - offx, py = qy - offy, pz = qz - offz;
    // dedupe (bit set on even component -> duplicate combo) + bounds
    bool valid = gok & ((sub & ~exmask & 7) == 0) &
                 ((unsigned)px < 256u) & ((unsigned)py < 256u) & ((unsigned)pz < 256u);
    int lin = (px >> 1) | ((py >> 1) << 7) | ((pz >> 1) << 14);
    int idx = table[valid ? lin : 0];   // replicated over ksec -> broadcast
    idx = valid ? idx : -1;
    int oi = (offx + 1) * 9 + (offy + 1) * 3 + (offz + 1);

    unsigned long long m = __ballot((idx >= 0) && (ksec == 0));
    unsigned gm = (unsigned)((m >> (half * 32)) & 0xffull);  // uniform in half
    bool exists = (gm != 0);

    float4 acc = make_float4(0.f, 0.f, 0.f, 0.f);

    while (gm) {
        int s = __builtin_ctz(gm);
        gm &= gm - 1;
        int src  = (half << 5) | s;
        int hidx = __shfl(idx, src, 64);
        int hoi  = __shfl(oi,  src, 64);

        const float4* f4 = (const float4*)(feats + (size_t)hidx * NIN) + ksec * 4;
        const float4* w4 = (const float4*)(weights + (size_t)hoi * (NIN * NOUT))
                           + ksec * 16 * (NOUT / 4) + sub;
        float4 f0 = f4[0], f1 = f4[1], f2 = f4[2], f3 = f4[3];

#define STEP(fv, base)                                                        \
        {                                                                     \
            float4 wa = w4[((base) + 0) * (NOUT / 4)];                        \
            float4 wb = w4[((base) + 1) * (NOUT / 4)];                        \
            float4 wc = w4[((base) + 2) * (NOUT / 4)];                        \
            float4 wd = w4[((base) + 3) * (NOUT / 4)];                        \
            acc.x = fmaf(fv.x, wa.x, acc.x); acc.y = fmaf(fv.x, wa.y, acc.y); \
            acc.z = fmaf(fv.x, wa.z, acc.z); acc.w = fmaf(fv.x, wa.w, acc.w); \
            acc.x = fmaf(fv.y, wb.x, acc.x); acc.y = fmaf(fv.y, wb.y, acc.y); \
            acc.z = fmaf(fv.y, wb.z, acc.z); acc.w = fmaf(fv.y, wb.w, acc.w); \
            acc.x = fmaf(fv.z, wc.x, acc.x); acc.y = fmaf(fv.z, wc.y, acc.y); \
            acc.z = fmaf(fv.z, wc.z, acc.z); acc.w = fmaf(fv.z, wc.w, acc.w); \
            acc.x = fmaf(fv.w, wd.x, acc.x); acc.y = fmaf(fv.w, wd.y, acc.y); \
            acc.z = fmaf(fv.w, wd.z, acc.z); acc.w = fmaf(fv.w, wd.w, acc.w); \
        }
        STEP(f0, 0) STEP(f1, 4) STEP(f2, 8) STEP(f3, 12)
#undef STEP
    }

    // reduce the 4 k-sections (lanes differing in bits 3,4 of lane id)
    acc.x += __shfl_xor(acc.x, 8, 64);  acc.y += __shfl_xor(acc.y, 8, 64);
    acc.z += __shfl_xor(acc.z, 8, 64);  acc.w += __shfl_xor(acc.w, 8, 64);
    acc.x += __shfl_xor(acc.x, 16, 64); acc.y += __shfl_xor(acc.y, 16, 64);
    acc.z += __shfl_xor(acc.z, 16, 64); acc.w += __shfl_xor(acc.w, 16, 64);

    if (gok && ksec == 0) {
        float4 r = make_float4(0.f, 0.f, 0.f, 0.f);
        if (exists) {
            float4 bv = ((const float4*)bias)[sub];
            r.x = acc.x + bv.x; r.y = acc.y + bv.y;
            r.z = acc.z + bv.z; r.w = acc.w + bv.w;
        }
        ((float4*)out)[(size_t)g * (NOUT / 4) + sub] = r;
    }
}

extern "C" void kernel_launch(void* const* d_in, const int* in_sizes, int n_in,
                              void* d_out, int out_size, void* d_ws, size_t ws_size,
                              hipStream_t stream) {
    const float* feats   = (const float*)d_in[0];
    const float* weights = (const float*)d_in[1];
    const float* bias    = (const float*)d_in[2];
    const int*   coords  = (const int*)d_in[3];
    const int*   guide   = (const int*)d_in[4];
    float* out = (float*)d_out;

    int np = in_sizes[3] / 4;
    int ng = in_sizes[4] / 4;

    int* table = (int*)d_ws;   // 2^21 * 4 B = 8 MB

    hipLaunchKernelGGL(init_table4, dim3(TSIZE / 4 / 256), dim3(256), 0, stream,
                       (int4*)table, TSIZE / 4);
    hipLaunchKernelGGL(build_table, dim3((np + 255) / 256), dim3(256), 0, stream,
                       coords, np, table);

    long long threads = (long long)ng * 32;
    int blocks = (int)((threads + 255) / 256);
    hipLaunchKernelGGL(gen_conv, dim3(blocks), dim3(256), 0, stream,
                       feats, weights, bias, guide, table, out, ng);
}

// Round 5
// 279.721 us; speedup vs baseline: 2.2131x; 1.1222x over previous
//
#include <hip/hip_runtime.h>

#define NIN 64
#define NOUT 32
#define TBITS 21                 // 128^3 stride-2 lattice
#define TSIZE (1 << TBITS)
#define WROW 36                  // bf16 elems per k-row in LDS (32 ch + 4 pad)

// ---- fill direct table with -1 (ws is poisoned 0xAA every call) ----
__global__ void init_table4(int4* __restrict__ table, int n4) {
    int i = blockIdx.x * blockDim.x + threadIdx.x;
    if (i < n4) table[i] = make_int4(-1, -1, -1, -1);
}

// ---- scatter input point indices into the dense stride-2 lattice table ----
__global__ void build_table(const int* __restrict__ coords, int np,
                            int* __restrict__ table) {
    int i = blockIdx.x * blockDim.x + threadIdx.x;
    if (i >= np) return;
    int x = coords[i * 4 + 1];
    int y = coords[i * 4 + 2];
    int z = coords[i * 4 + 3];
    table[(x >> 1) | ((y >> 1) << 7) | ((z >> 1) << 14)] = i;
}

// ---- main: all 27 weight matrices LDS-resident as bf16 (124 KB, 1 block/CU,
// 16 waves). One guide per 64-lane wave: lane=(ksec 0..7, sub 0..7); sub is
// both probe slot and channel-quad; ksec splits k 8 ways. Row pad (WROW=36)
// puts ds_read_b64 at the 4-lane/bank wave64 floor. Two hits extracted per
// loop iter for feat-load MLP. 3x shfl_xor reduces the 8 k-sections. ----
__launch_bounds__(1024, 4)
__global__ void gen_conv(const float* __restrict__ feats,     // [Np,64]
                         const float* __restrict__ weights,   // [27,64,32]
                         const float* __restrict__ bias,      // [32]
                         const int*  __restrict__ guide,      // [Ng,4]
                         const int*  __restrict__ table,      // [2^21]
                         float* __restrict__ out, int ng) {
    __shared__ unsigned short wlds[27 * 64 * WROW];   // 124416 B

    // stage weights fp32 -> bf16 (round-to-nearest-even), padded rows
    for (int e = threadIdx.x; e < 27 * 64 * 32; e += 1024) {
        int row = e >> 5;            // oi*64 + k
        int ch  = e & 31;
        unsigned u = __float_as_uint(weights[e]);
        u += 0x7fffu + ((u >> 16) & 1u);
        wlds[row * WROW + ch] = (unsigned short)(u >> 16);
    }
    __syncthreads();

    int lane = threadIdx.x & 63;
    int sub  = lane & 7;             // probe slot AND channel-quad id
    int ksec = lane >> 3;            // k section: k = ksec*8 + j
    int wave   = blockIdx.x * (blockDim.x >> 6) + (threadIdx.x >> 6);
    int nwaves = gridDim.x * (blockDim.x >> 6);

    float4 bv = ((const float4*)bias)[sub];
    int b0 = sub & 1, b1 = (sub >> 1) & 1, b2 = (sub >> 2) & 1;

    for (int g = wave; g < ng; g += nwaves) {
        int4 q = ((const int4*)guide)[g];        // wave-broadcast
        int qx = q.y, qy = q.z, qz = q.w;
        int ex = qx & 1, ey = qy & 1, ez = qz & 1;
        int exmask = ex | (ey << 1) | (ez << 2);
        int offx = ex ? (b0 ? 1 : -1) : 0;
        int offy = ey ? (b1 ? 1 : -1) : 0;
        int offz = ez ? (b2 ? 1 : -1) : 0;
        int px = qx - offx, py = qy - offy, pz = qz - offz;
        bool valid = ((sub & ~exmask & 7) == 0) &
                     ((unsigned)px < 256u) & ((unsigned)py < 256u) & ((unsigned)pz < 256u);
        int lin = (px >> 1) | ((py >> 1) << 7) | ((pz >> 1) << 14);
        int idx = table[valid ? lin : 0];        // replicated over ksec -> broadcast
        idx = valid ? idx : -1;
        int oi = (offx + 1) * 9 + (offy + 1) * 3 + (offz + 1);

        unsigned long long m = __ballot(idx >= 0);
        unsigned gm = (unsigned)(m & 0xffull);   // lanes 0..7 carry the 8 slots
        bool exists = (gm != 0);

        float4 acc = make_float4(0.f, 0.f, 0.f, 0.f);

        while (gm) {
            int s0 = __builtin_ctz(gm); gm &= gm - 1;
            int s1 = gm ? __builtin_ctz(gm) : -1;
            if (s1 >= 0) gm &= gm - 1;
            int h0 = __shfl(idx, s0, 64);
            int o0 = __shfl(oi,  s0, 64);
            int h1 = __shfl(idx, (s1 >= 0 ? s1 : s0), 64);
            int o1 = __shfl(oi,  (s1 >= 0 ? s1 : s0), 64);

            const float4* fp0 = (const float4*)(feats + (size_t)h0 * NIN + ksec * 8);
            float4 fa0 = fp0[0], fb0 = fp0[1];
            float4 fa1 = fa0, fb1 = fb0;
            if (s1 >= 0) {
                const float4* fp1 = (const float4*)(feats + (size_t)h1 * NIN + ksec * 8);
                fa1 = fp1[0]; fb1 = fp1[1];
            }

#define HIT_BODY(O, FA, FB)                                                    \
            {                                                                  \
                const unsigned short* wb =                                     \
                    wlds + ((O) * 64 + ksec * 8) * WROW + sub * 4;             \
                _Pragma("unroll")                                              \
                for (int j = 0; j < 8; ++j) {                                  \
                    uint2 w = *(const uint2*)(wb + j * WROW);                  \
                    float fk = (j < 4) ? ((const float*)&FA)[j]                \
                                       : ((const float*)&FB)[j - 4];           \
                    acc.x = fmaf(fk, __uint_as_float(w.x << 16), acc.x);       \
                    acc.y = fmaf(fk, __uint_as_float(w.x & 0xffff0000u), acc.y);\
                    acc.z = fmaf(fk, __uint_as_float(w.y << 16), acc.z);       \
                    acc.w = fmaf(fk, __uint_as_float(w.y & 0xffff0000u), acc.w);\
                }                                                              \
            }
            HIT_BODY(o0, fa0, fb0)
            if (s1 >= 0) HIT_BODY(o1, fa1, fb1)
#undef HIT_BODY
        }

        // reduce the 8 k-sections (ksec lives in lane bits 3..5)
        acc.x += __shfl_xor(acc.x, 8, 64);  acc.y += __shfl_xor(acc.y, 8, 64);
        acc.z += __shfl_xor(acc.z, 8, 64);  acc.w += __shfl_xor(acc.w, 8, 64);
        acc.x += __shfl_xor(acc.x, 16, 64); acc.y += __shfl_xor(acc.y, 16, 64);
        acc.z += __shfl_xor(acc.z, 16, 64); acc.w += __shfl_xor(acc.w, 16, 64);
        acc.x += __shfl_xor(acc.x, 32, 64); acc.y += __shfl_xor(acc.y, 32, 64);
        acc.z += __shfl_xor(acc.z, 32, 64); acc.w += __shfl_xor(acc.w, 32, 64);

        if (ksec == 0) {
            float4 r = make_float4(0.f, 0.f, 0.f, 0.f);
            if (exists) {
                r.x = acc.x + bv.x; r.y = acc.y + bv.y;
                r.z = acc.z + bv.z; r.w = acc.w + bv.w;
            }
            ((float4*)out)[(size_t)g * (NOUT / 4) + sub] = r;
        }
    }
}

extern "C" void kernel_launch(void* const* d_in, const int* in_sizes, int n_in,
                              void* d_out, int out_size, void* d_ws, size_t ws_size,
                              hipStream_t stream) {
    const float* feats   = (const float*)d_in[0];
    const float* weights = (const float*)d_in[1];
    const float* bias    = (const float*)d_in[2];
    const int*   coords  = (const int*)d_in[3];
    const int*   guide   = (const int*)d_in[4];
    float* out = (float*)d_out;

    int np = in_sizes[3] / 4;
    int ng = in_sizes[4] / 4;

    int* table = (int*)d_ws;   // 2^21 * 4 B = 8 MB

    hipLaunchKernelGGL(init_table4, dim3(TSIZE / 4 / 256), dim3(256), 0, stream,
                       (int4*)table, TSIZE / 4);
    hipLaunchKernelGGL(build_table, dim3((np + 255) / 256), dim3(256), 0, stream,
                       coords, np, table);

    hipLaunchKernelGGL(gen_conv, dim3(512), dim3(1024), 0, stream,
                       feats, weights, bias, guide, table, out, ng);
}

// Round 6
// 230.139 us; speedup vs baseline: 2.6899x; 1.2154x over previous
//
#include <hip/hip_runtime.h>

#define NIN 64
#define NOUT 32
#define TBITS 21                 // 128^3 stride-2 lattice
#define TSIZE (1 << TBITS)

typedef __attribute__((ext_vector_type(8))) short short8;
typedef __attribute__((ext_vector_type(4))) float float4v;

__device__ __forceinline__ unsigned short bf16rne(float x) {
    unsigned u = __float_as_uint(x);
    u += 0x7fffu + ((u >> 16) & 1u);
    return (unsigned short)(u >> 16);
}

// ws (ints): [0,2M) table | [2M, 2M+ng+128) sorted(-1 padded) |
//            A=2M+ng+128: count[8] | pbase[9] at A+8 | cursor[8] at A+20 |
//            wt bf16 [27][32][64] at int offset A+32
// init table+sorted to -1 (contiguous), zero count
__global__ void init_all(int4* __restrict__ ws4, int n4, int* __restrict__ count) {
    int i = blockIdx.x * blockDim.x + threadIdx.x;
    if (i < n4) ws4[i] = make_int4(-1, -1, -1, -1);
    if (i < 8) count[i] = 0;
}

__global__ void build_table(const int* __restrict__ coords, int np,
                            int* __restrict__ table) {
    int i = blockIdx.x * blockDim.x + threadIdx.x;
    if (i >= np) return;
    int x = coords[i * 4 + 1];
    int y = coords[i * 4 + 2];
    int z = coords[i * 4 + 3];
    table[(x >> 1) | ((y >> 1) << 7) | ((z >> 1) << 14)] = i;
}

__global__ void count_classes(const int* __restrict__ guide, int ng,
                              int* __restrict__ count) {
    __shared__ int lc[8];
    if (threadIdx.x < 8) lc[threadIdx.x] = 0;
    __syncthreads();
    int g = blockIdx.x * blockDim.x + threadIdx.x;
    if (g < ng) {
        int4 q = ((const int4*)guide)[g];
        int c = (q.y & 1) | ((q.z & 1) << 1) | ((q.w & 1) << 2);
        atomicAdd(&lc[c], 1);
    }
    __syncthreads();
    if (threadIdx.x < 8 && lc[threadIdx.x]) atomicAdd(&count[threadIdx.x], lc[threadIdx.x]);
}

// 16-aligned padded exclusive scan; seed cursor
__global__ void scan8(const int* __restrict__ count, int* __restrict__ pbase,
                      int* __restrict__ cursor) {
    if (threadIdx.x == 0 && blockIdx.x == 0) {
        int s = 0;
        for (int c = 0; c < 8; ++c) {
            pbase[c] = s; cursor[c] = s;
            s += (count[c] + 15) & ~15;
        }
        pbase[8] = s;
    }
}

__global__ void scatter_guides(const int* __restrict__ guide, int ng,
                               int* __restrict__ cursor, int* __restrict__ sorted) {
    __shared__ int lc[8];
    __shared__ int lbase[8];
    int t = threadIdx.x;
    if (t < 8) lc[t] = 0;
    __syncthreads();
    int g = blockIdx.x * blockDim.x + t;
    int c = 0, lrank = 0;
    bool ok = g < ng;
    if (ok) {
        int4 q = ((const int4*)guide)[g];
        c = (q.y & 1) | ((q.z & 1) << 1) | ((q.w & 1) << 2);
        lrank = atomicAdd(&lc[c], 1);
    }
    __syncthreads();
    if (t < 8) lbase[t] = lc[t] ? atomicAdd(&cursor[t], lc[t]) : 0;
    __syncthreads();
    if (ok) sorted[lbase[c] + lrank] = g;
}

// fp32 [27][64][32] -> bf16 transposed [27][32][64]
__global__ void wcvt(const float* __restrict__ w, unsigned short* __restrict__ wt) {
    int i = blockIdx.x * blockDim.x + threadIdx.x;
    if (i < 27 * 64 * 32) {
        int oi = i >> 11;
        int k  = (i >> 5) & 63;
        int ch = i & 31;
        wt[oi * 2048 + ch * 64 + k] = bf16rne(w[i]);
    }
}

// ---- main: one wave per tile of 16 same-parity-class guides.
// Probe: lane=(slot 0..3, m 0..15), 2 rounds -> idx0/idx1 + ballots.
// GEMM: per admissible slot, A[16x64] gathered bf16 (miss rows skip load),
// B from global bf16 wt, 4x mfma_f32_16x16x32_bf16 into two f32x4 accs.
// C layout: col(n)=lane&15, row(m)=quad*4+reg. ----
__launch_bounds__(256, 4)
__global__ void gen_conv(const float* __restrict__ feats,        // [Np,64]
                         const float* __restrict__ bias,         // [32]
                         const int* __restrict__ guide,          // [Ng,4]
                         const int* __restrict__ table,          // [2^21]
                         const int* __restrict__ sorted,         // padded
                         const int* __restrict__ pbase,          // [9]
                         const unsigned short* __restrict__ wt,  // [27][32][64] bf16
                         float* __restrict__ out, int ng) {
    int tile = blockIdx.x * 4 + (threadIdx.x >> 6);
    int lane = threadIdx.x & 63;
    int m    = lane & 15;          // guide-row in tile / B n-col
    int quad = lane >> 4;          // k-octet / probe slot base

    int total = pbase[8];
    int t16 = tile * 16;
    if (t16 >= total) return;

    // class of this tile (pbase monotone)
    int c = 0;
    #pragma unroll
    for (int j = 1; j < 8; ++j) c += (t16 >= pbase[j]) ? 1 : 0;
    c = __builtin_amdgcn_readfirstlane(c);
    int ex = c & 1, ey = (c >> 1) & 1, ez = (c >> 2) & 1;

    int id = sorted[t16 + m];
    int4 q = ((const int4*)guide)[id < 0 ? 0 : id];
    int qx = q.y, qy = q.z, qz = q.w;

    // probe rounds: sub = quad (round0), quad+4 (round1)
    int idxr[2];
    #pragma unroll
    for (int r = 0; r < 2; ++r) {
        int sub = quad + r * 4;
        int offx = ex ? ((sub & 1) ? 1 : -1) : 0;
        int offy = ey ? ((sub & 2) ? 1 : -1) : 0;
        int offz = ez ? ((sub & 4) ? 1 : -1) : 0;
        int px = qx - offx, py = qy - offy, pz = qz - offz;
        bool valid = (id >= 0) & ((sub & ~c & 7) == 0) &
                     ((unsigned)px < 256u) & ((unsigned)py < 256u) & ((unsigned)pz < 256u);
        int lin = (px >> 1) | ((py >> 1) << 7) | ((pz >> 1) << 14);
        int v = table[valid ? lin : 0];
        idxr[r] = valid ? v : -1;
    }

    unsigned long long bal0 = __ballot(idxr[0] >= 0);
    unsigned long long bal1 = __ballot(idxr[1] >= 0);
    unsigned long long eb = bal0 | bal1;
    unsigned e16 = (unsigned)((eb | (eb >> 16) | (eb >> 32) | (eb >> 48)) & 0xffffull);

    float4v acc0 = {0.f, 0.f, 0.f, 0.f};
    float4v acc1 = {0.f, 0.f, 0.f, 0.f};

    #pragma unroll
    for (int sub = 0; sub < 8; ++sub) {
        if (sub & ~c & 7) continue;    // inadmissible for this class (uniform)
        unsigned long long bal = (sub < 4) ? bal0 : bal1;
        unsigned rowm = (unsigned)((bal >> ((sub & 3) * 16)) & 0xffffull);
        if (rowm == 0) continue;

        int srcl = (sub & 3) * 16 + m;
        int hidx = __shfl((sub < 4) ? idxr[0] : idxr[1], srcl, 64);

        // A fragments: row m, k = quad*8+j (a0: k<32, a1: k>=32)
        short8 a0 = {0,0,0,0,0,0,0,0};
        short8 a1 = {0,0,0,0,0,0,0,0};
        if (hidx >= 0) {
            const float4* fp = (const float4*)(feats + (size_t)hidx * NIN + quad * 8);
            float4 fA = fp[0], fB = fp[1];
            const float4* fp2 = (const float4*)(feats + (size_t)hidx * NIN + 32 + quad * 8);
            float4 fC = fp2[0], fD = fp2[1];
            a0[0] = (short)bf16rne(fA.x); a0[1] = (short)bf16rne(fA.y);
            a0[2] = (short)bf16rne(fA.z); a0[3] = (short)bf16rne(fA.w);
            a0[4] = (short)bf16rne(fB.x); a0[5] = (short)bf16rne(fB.y);
            a0[6] = (short)bf16rne(fB.z); a0[7] = (short)bf16rne(fB.w);
            a1[0] = (short)bf16rne(fC.x); a1[1] = (short)bf16rne(fC.y);
            a1[2] = (short)bf16rne(fC.z); a1[3] = (short)bf16rne(fC.w);
            a1[4] = (short)bf16rne(fD.x); a1[5] = (short)bf16rne(fD.y);
            a1[6] = (short)bf16rne(fD.z); a1[7] = (short)bf16rne(fD.w);
        }

        int offx = ex ? ((sub & 1) ? 1 : -1) : 0;
        int offy = ey ? ((sub & 2) ? 1 : -1) : 0;
        int offz = ez ? ((sub & 4) ? 1 : -1) : 0;
        int oi = (offx + 1) * 9 + (offy + 1) * 3 + (offz + 1);

        // B fragments: lane holds B[k=quad*8+j][n=m]; wt[oi][ch][k]
        const unsigned short* wb = wt + oi * 2048 + m * 64 + quad * 8;
        short8 b00 = *(const short8*)(wb);               // k<32,  ch m
        short8 b01 = *(const short8*)(wb + 1024);        // k<32,  ch 16+m
        short8 b10 = *(const short8*)(wb + 32);          // k>=32, ch m
        short8 b11 = *(const short8*)(wb + 1024 + 32);   // k>=32, ch 16+m

        acc0 = __builtin_amdgcn_mfma_f32_16x16x32_bf16(a0, b00, acc0, 0, 0, 0);
        acc0 = __builtin_amdgcn_mfma_f32_16x16x32_bf16(a1, b10, acc0, 0, 0, 0);
        acc1 = __builtin_amdgcn_mfma_f32_16x16x32_bf16(a0, b01, acc1, 0, 0, 0);
        acc1 = __builtin_amdgcn_mfma_f32_16x16x32_bf16(a1, b11, acc1, 0, 0, 0);
    }

    // store: lane's col n=m; rows mr=quad*4+r
    float bv0 = bias[m], bv1 = bias[16 + m];
    #pragma unroll
    for (int r = 0; r < 4; ++r) {
        int mr = quad * 4 + r;
        int idr = __shfl(id, mr, 64);      // lanes 0..15 hold the 16 ids
        if (idr >= 0) {
            bool exr = (e16 >> mr) & 1;
            float v0 = exr ? (acc0[r] + bv0) : 0.f;
            float v1 = exr ? (acc1[r] + bv1) : 0.f;
            out[(size_t)idr * NOUT + m]      = v0;
            out[(size_t)idr * NOUT + 16 + m] = v1;
        }
    }
}

extern "C" void kernel_launch(void* const* d_in, const int* in_sizes, int n_in,
                              void* d_out, int out_size, void* d_ws, size_t ws_size,
                              hipStream_t stream) {
    const float* feats   = (const float*)d_in[0];
    const float* weights = (const float*)d_in[1];
    const float* bias    = (const float*)d_in[2];
    const int*   coords  = (const int*)d_in[3];
    const int*   guide   = (const int*)d_in[4];
    float* out = (float*)d_out;

    int np = in_sizes[3] / 4;
    int ng = in_sizes[4] / 4;

    int* wsI = (int*)d_ws;
    int* table  = wsI;                       // 2^21
    int* sorted = wsI + TSIZE;               // ng+128, -1 padded
    int A = TSIZE + ng + 128;
    int* count  = wsI + A;                   // 8
    int* pbase  = wsI + A + 8;               // 9
    int* cursor = wsI + A + 20;              // 8
    unsigned short* wt = (unsigned short*)(wsI + A + 32);   // 27*32*64 bf16

    int n4 = (TSIZE + ng + 128 + 3) / 4;
    hipLaunchKernelGGL(init_all, dim3((n4 + 255) / 256), dim3(256), 0, stream,
                       (int4*)wsI, n4, count);
    hipLaunchKernelGGL(build_table, dim3((np + 255) / 256), dim3(256), 0, stream,
                       coords, np, table);
    hipLaunchKernelGGL(count_classes, dim3((ng + 255) / 256), dim3(256), 0, stream,
                       guide, ng, count);
    hipLaunchKernelGGL(scan8, dim3(1), dim3(64), 0, stream, count, pbase, cursor);
    hipLaunchKernelGGL(scatter_guides, dim3((ng + 255) / 256), dim3(256), 0, stream,
                       guide, ng, cursor, sorted);
    hipLaunchKernelGGL(wcvt, dim3((27 * 64 * 32 + 255) / 256), dim3(256), 0, stream,
                       weights, wt);

    int maxtiles = (ng + 8 * 15 + 15) / 16;
    int blocks = (maxtiles + 3) / 4;         // 4 waves (tiles) per block
    hipLaunchKernelGGL(gen_conv, dim3(blocks), dim3(256), 0, stream,
                       feats, bias, guide, table, sorted, pbase, wt, out, ng);
}